// Round 7
// baseline (228.556 us; speedup 1.0000x reference)
//
#include <hip/hip_runtime.h>
#include <hip/hip_bf16.h>

typedef __bf16 bf16;
typedef __bf16 bf16x4 __attribute__((ext_vector_type(4)));
typedef __bf16 bf16x8 __attribute__((ext_vector_type(8)));
typedef float f32x4 __attribute__((ext_vector_type(4)));

#define B_ 4
#define C_ 256
#define NH_ 4
#define KD_ 32
#define HD_ 64
#define N_ 4096
#define HQKV_ 512

// ---------------- weight convert ----------------
__global__ __launch_bounds__(256) void k_convw(const float* wq, const float* wp,
                                               bf16* wqb, bf16* wpb) {
    int i = blockIdx.x * 256 + threadIdx.x;
    if (i < HQKV_ * C_) wqb[i] = (bf16)wq[i];
    if (i < C_ * C_)    wpb[i] = (bf16)wp[i];
}

// ---------------- x (B,C,N) f32 -> xT (B,N,C) bf16 ----------------
__global__ __launch_bounds__(256) void k_transpose(const float* __restrict__ x,
                                                   bf16* __restrict__ xT) {
    __shared__ float tile[64][65];
    int b = blockIdx.z, c0 = blockIdx.y * 64, n0 = blockIdx.x * 64;
    int t = threadIdx.x;
    int lane = t & 63, wv = t >> 6;
    for (int k = 0; k < 16; ++k) {
        int cl = k * 4 + wv;
        tile[cl][lane] = x[((size_t)(b * C_ + c0 + cl)) * N_ + n0 + lane];
    }
    __syncthreads();
    for (int k = 0; k < 16; ++k) {
        int nl = k * 4 + wv;
        xT[((size_t)(b * N_ + n0 + nl)) * C_ + c0 + lane] = (bf16)tile[lane][nl];
    }
}

// ---------------- qkv GEMM: W(512x256) @ xT^T, writes q_t,k_t,(B,NH,N,32) v(B,NH,64,N) ----------------
__global__ __launch_bounds__(256) void k_qkv(const bf16* __restrict__ wqb,
                                             const bf16* __restrict__ xT,
                                             const float* __restrict__ bias,
                                             bf16* __restrict__ qt, bf16* __restrict__ kt,
                                             bf16* __restrict__ vb) {
    int n0 = blockIdx.x * 64, o0 = blockIdx.y * 64, b = blockIdx.z;
    int t = threadIdx.x, w = t >> 6, l = t & 63, lr = l & 15, lg = l >> 4;
    const bf16* arow = wqb + (size_t)(o0 + 16 * w + lr) * C_ + 8 * lg;
    const bf16* brow = xT + ((size_t)b * N_ + n0 + lr) * C_ + 8 * lg;
    f32x4 acc[4];
    f32x4 zz = {0.f, 0.f, 0.f, 0.f};
    acc[0] = zz; acc[1] = zz; acc[2] = zz; acc[3] = zz;
    for (int kk = 0; kk < C_; kk += 32) {
        bf16x8 a = *(const bf16x8*)(arow + kk);
#pragma unroll
        for (int tt = 0; tt < 4; ++tt) {
            bf16x8 bb = *(const bf16x8*)(brow + (size_t)tt * 16 * C_ + kk);
            acc[tt] = __builtin_amdgcn_mfma_f32_16x16x32_bf16(a, bb, acc[tt], 0, 0, 0);
        }
    }
    // KD^-0.5 * log2(e) folded into q so attention can use raw exp2
    const float scale = 0.25506953076085663f;
#pragma unroll
    for (int tt = 0; tt < 4; ++tt) {
        int n = n0 + 16 * tt + lr;
#pragma unroll
        for (int j = 0; j < 4; ++j) {
            int o = o0 + 16 * w + 4 * lg + j;
            float val = acc[tt][j] + bias[o];
            int h = o >> 7, r = o & 127;
            size_t bh = (size_t)(b * NH_ + h);
            if (r < KD_)            qt[(bh * N_ + n) * KD_ + r] = (bf16)(val * scale);
            else if (r < 2 * KD_)   kt[(bh * N_ + n) * KD_ + (r - KD_)] = (bf16)val;
            else                    vb[(bh * HD_ + (r - 2 * KD_)) * N_ + n] = (bf16)val;
        }
    }
}

// ---------------- fused flash attention: 16 q-rows/wave, 32KB LDS, 4 blocks/CU ----------------
// K/V double-buffered (1 barrier/iter); P per-wave [16][64] XOR slot-swizzled
// (slot ^= row&7, same involution write/read side). XCD-confined: id&15 = bh.
__global__ __launch_bounds__(256, 4) void k_attn(const bf16* __restrict__ qt,
                                                 const bf16* __restrict__ kt,
                                                 const bf16* __restrict__ vb,
                                                 bf16* __restrict__ attnT) {
    __shared__ bf16 ldsK[2][64 * KD_];   // 8KB  [m][k], slot(16B) ^= m&3
    __shared__ bf16 ldsV[2][64 * 64];    // 16KB [d][m], slot(16B) ^= d&7
    __shared__ bf16 ldsP[4][16 * 64];    // 8KB  per-wave [n][m], slot(16B) ^= n&7
    int id = blockIdx.x;
    int bh = id & 15;            // id%8 == bh%8 -> 2 heads' K/V per XCD L2
    int n0 = (id >> 4) * 64;
    int b = bh >> 2, h = bh & 3;
    int t = threadIdx.x, w = t >> 6, l = t & 63, lr = l & 15, lg = l >> 4;

    bf16x8 aq = *(const bf16x8*)(qt + ((size_t)bh * N_ + n0 + 16 * w + lr) * KD_ + 8 * lg);

    int krow = 16 * w + (l >> 2);
    const bf16* kg = kt + ((size_t)bh * N_ + krow) * KD_ + 8 * (l & 3);
    int kwo = krow * KD_ + 8 * ((l & 3) ^ (krow & 3));
    int vrow = 16 * w + (l >> 3);
    const bf16* vg = vb + ((size_t)bh * HD_ + vrow) * N_ + 8 * (l & 7);
    int vwo = vrow * 64 + 8 * ((l & 7) ^ (vrow & 7));   // row+8 shares the XOR (vrow&7 invariant)

    f32x4 zz = {0.f, 0.f, 0.f, 0.f};
    f32x4 Lacc = zz;
    f32x4 oacc[4];
    oacc[0] = zz; oacc[1] = zz; oacc[2] = zz; oacc[3] = zz;
    char* myp = (char*)&ldsP[w][0];

    bf16x8 rk  = *(const bf16x8*)(kg);
    bf16x8 rv0 = *(const bf16x8*)(vg);
    bf16x8 rv1 = *(const bf16x8*)(vg + (size_t)8 * N_);

    int cur = 0;
    for (int m0 = 0; m0 < N_; m0 += 64, cur ^= 1) {
        *(bf16x8*)(&ldsK[cur][0] + kwo) = rk;
        *(bf16x8*)(&ldsV[cur][0] + vwo) = rv0;
        *(bf16x8*)(&ldsV[cur][0] + vwo + 8 * 64) = rv1;
        if (m0 + 64 < N_) {
            rk  = *(const bf16x8*)(kg + (size_t)(m0 + 64) * KD_);
            rv0 = *(const bf16x8*)(vg + m0 + 64);
            rv1 = *(const bf16x8*)(vg + (size_t)8 * N_ + m0 + 64);
        }
        __syncthreads();
        const bf16* kb_ = &ldsK[cur][0];
        const bf16* vb_ = &ldsV[cur][0];

        f32x4 s[4];
        __builtin_amdgcn_s_setprio(1);
#pragma unroll
        for (int tt = 0; tt < 4; ++tt) {
            bf16x8 kf = *(const bf16x8*)(kb_ + (16 * tt + lr) * KD_ + 8 * (lg ^ (lr & 3)));
            s[tt] = __builtin_amdgcn_mfma_f32_16x16x32_bf16(kf, aq, zz, 0, 0, 0);
        }
        __builtin_amdgcn_s_setprio(0);
        // exp + P write: row=n=lr, col m=16tt+4lg(+j); stored-slot=(2tt+(lg>>1))^(lr&7), sub=8*(lg&1)
#pragma unroll
        for (int tt = 0; tt < 4; ++tt) {
            f32x4 pv;
#pragma unroll
            for (int j = 0; j < 4; ++j) pv[j] = __builtin_amdgcn_exp2f(s[tt][j]);
            Lacc += pv;
            bf16x4 pk;
#pragma unroll
            for (int j = 0; j < 4; ++j) pk[j] = (bf16)pv[j];
            *(bf16x4*)(myp + lr * 128 + (((2 * tt + (lg >> 1)) ^ (lr & 7)) << 4) + 8 * (lg & 1)) = pk;
        }
        // PV: A-frag row=lr, k=8lg..+7 of m-chunk 32ks -> slot=(4ks+lg)^(lr&7)
        __builtin_amdgcn_s_setprio(1);
#pragma unroll
        for (int ks = 0; ks < 2; ++ks) {
            bf16x8 pa = *(const bf16x8*)(myp + lr * 128 + (((4 * ks + lg) ^ (lr & 7)) << 4));
#pragma unroll
            for (int dt = 0; dt < 4; ++dt) {
                bf16x8 vf = *(const bf16x8*)(vb_ + (16 * dt + lr) * 64 + 8 * ((4 * ks + lg) ^ (lr & 7)));
                oacc[dt] = __builtin_amdgcn_mfma_f32_16x16x32_bf16(pa, vf, oacc[dt], 0, 0, 0);
            }
        }
        __builtin_amdgcn_s_setprio(0);
    }
    float Lp = Lacc[0] + Lacc[1] + Lacc[2] + Lacc[3];
    Lp += __shfl_xor(Lp, 16);
    Lp += __shfl_xor(Lp, 32);
    float inv[4];
#pragma unroll
    for (int j = 0; j < 4; ++j) inv[j] = 1.f / __shfl(Lp, 4 * lg + j);
#pragma unroll
    for (int dt = 0; dt < 4; ++dt)
#pragma unroll
        for (int j = 0; j < 4; ++j) {
            int n = n0 + 16 * w + 4 * lg + j;
            int d = h * HD_ + 16 * dt + lr;
            attnT[((size_t)b * N_ + n) * C_ + d] = (bf16)(oacc[dt][j] * inv[j]);
        }
}

// ---------------- y = attn + dwconv3(v)+b_pe; writes yT (B,N,C) bf16 ----------------
__global__ __launch_bounds__(256) void k_pe_add(const bf16* __restrict__ attnT,
                                                const bf16* __restrict__ vb,
                                                const float* __restrict__ wpe,
                                                const float* __restrict__ bpe,
                                                bf16* __restrict__ yT) {
    __shared__ float vt[64 * 199];  // [c_local][kh*66 + wslot], wslot = w+1, pads at 0 and 65
    int hh = blockIdx.x, c0 = blockIdx.y * 64, b = blockIdx.z;
    int t = threadIdx.x, lane = t & 63, wg = t >> 6;

    if (t < 192) {
        int c_l = t >> 2, kh2 = t & 3;
        if (kh2 < 3) {
            vt[c_l * 199 + kh2 * 66 + 0] = 0.f;
            vt[c_l * 199 + kh2 * 66 + 65] = 0.f;
        }
    }
    if (t >= 192) {
        int u = t - 192;
        int c_l = 48 + (u >> 2), kh2 = u & 3;
        if (kh2 < 3) {
            vt[c_l * 199 + kh2 * 66 + 0] = 0.f;
            vt[c_l * 199 + kh2 * 66 + 65] = 0.f;
        }
    }
#pragma unroll
    for (int kh = 0; kh < 3; ++kh) {
        int hh2 = hh + kh - 1;
        bool ok = (hh2 >= 0 && hh2 < 64);
        for (int ci = 0; ci < 16; ++ci) {
            int c_l = wg * 16 + ci;
            float val = ok ? (float)vb[((size_t)(b * C_ + c0 + c_l)) * N_ + hh2 * 64 + lane] : 0.f;
            vt[c_l * 199 + kh * 66 + 1 + lane] = val;
        }
    }
    __syncthreads();

    int c = c0 + lane;
    float w9[9];
#pragma unroll
    for (int k = 0; k < 9; ++k) w9[k] = wpe[c * 9 + k];
    float bc = bpe[c];
    const float* vrow = vt + lane * 199;

#pragma unroll
    for (int wi = 0; wi < 16; ++wi) {
        int w = wg * 16 + wi;
        float acc = bc;
#pragma unroll
        for (int kh = 0; kh < 3; ++kh)
#pragma unroll
            for (int kw = 0; kw < 3; ++kw)
                acc += vrow[kh * 66 + w + kw] * w9[kh * 3 + kw];
        int n = hh * 64 + w;
        size_t idx = ((size_t)b * N_ + n) * C_ + c;
        yT[idx] = (bf16)((float)attnT[idx] + acc);
    }
}

// ---------------- proj GEMM + residual: x2 = x + Wp @ y + b ----------------
__global__ __launch_bounds__(256) void k_proj(const bf16* __restrict__ wpb,
                                              const bf16* __restrict__ yT,
                                              const float* __restrict__ bias,
                                              const float* __restrict__ x,
                                              float* __restrict__ x2) {
    int n0 = blockIdx.x * 64, o0 = blockIdx.y * 64, b = blockIdx.z;
    int t = threadIdx.x, w = t >> 6, l = t & 63, lr = l & 15, lg = l >> 4;
    const bf16* arow = wpb + (size_t)(o0 + 16 * w + lr) * C_ + 8 * lg;
    const bf16* brow = yT + ((size_t)b * N_ + n0 + lr) * C_ + 8 * lg;
    f32x4 acc[4];
    f32x4 zz = {0.f, 0.f, 0.f, 0.f};
    acc[0] = zz; acc[1] = zz; acc[2] = zz; acc[3] = zz;
    for (int kk = 0; kk < C_; kk += 32) {
        bf16x8 a = *(const bf16x8*)(arow + kk);
#pragma unroll
        for (int tt = 0; tt < 4; ++tt) {
            bf16x8 bb = *(const bf16x8*)(brow + (size_t)tt * 16 * C_ + kk);
            acc[tt] = __builtin_amdgcn_mfma_f32_16x16x32_bf16(a, bb, acc[tt], 0, 0, 0);
        }
    }
#pragma unroll
    for (int tt = 0; tt < 4; ++tt) {
        int n = n0 + 16 * tt + lr;
#pragma unroll
        for (int j = 0; j < 4; ++j) {
            int o = o0 + 16 * w + 4 * lg + j;
            size_t idx = ((size_t)b * C_ + o) * N_ + n;
            x2[idx] = x[idx] + acc[tt][j] + bias[o];
        }
    }
}

// ---------------- channel attention: reduce ----------------
__global__ __launch_bounds__(256) void k_ca_red(const float* __restrict__ x2,
                                                float* __restrict__ avg, float* __restrict__ mx) {
    int bc = blockIdx.x;
    int t = threadIdx.x;
    const float* row = x2 + (size_t)bc * N_;
    float s = 0.f, m = -1e30f;
    for (int i = t; i < N_; i += 256) { float v = row[i]; s += v; m = fmaxf(m, v); }
#pragma unroll
    for (int d = 1; d < 64; d <<= 1) { s += __shfl_xor(s, d); m = fmaxf(m, __shfl_xor(m, d)); }
    __shared__ float ss[4], sm[4];
    int w = t >> 6;
    if ((t & 63) == 0) { ss[w] = s; sm[w] = m; }
    __syncthreads();
    if (t == 0) {
        avg[bc] = (ss[0] + ss[1] + ss[2] + ss[3]) / (float)N_;
        mx[bc] = fmaxf(fmaxf(sm[0], sm[1]), fmaxf(sm[2], sm[3]));
    }
}

// ---------------- channel attention: MLP ----------------
__global__ __launch_bounds__(256) void k_ca_mlp(const float* __restrict__ avg,
                                                const float* __restrict__ mx,
                                                const float* __restrict__ wfc1,
                                                const float* __restrict__ wfc2,
                                                float* __restrict__ ca) {
    int b = blockIdx.x, t = threadIdx.x;
    __shared__ float hsum[16];
    if (t < 16) {
        const float* w1 = wfc1 + t * C_;
        float ha = 0.f, hm = 0.f;
        for (int c = 0; c < C_; ++c) { ha += avg[b * C_ + c] * w1[c]; hm += mx[b * C_ + c] * w1[c]; }
        hsum[t] = fmaxf(ha, 0.f) + fmaxf(hm, 0.f);
    }
    __syncthreads();
    float o = 0.f;
    const float* w2 = wfc2 + t * 16;
#pragma unroll
    for (int r = 0; r < 16; ++r) o += hsum[r] * w2[r];
    ca[b * C_ + t] = 1.f / (1.f + __expf(-o));
}

// ---------------- spatial attention: channel reduce of x2*ca ----------------
__global__ __launch_bounds__(256) void k_sa_red(const float* __restrict__ x2,
                                                const float* __restrict__ ca,
                                                float* __restrict__ sain) {
    int b = blockIdx.y;
    int n = blockIdx.x * 256 + threadIdx.x;
    __shared__ float cal[C_];
    cal[threadIdx.x] = ca[b * C_ + threadIdx.x];
    __syncthreads();
    float s = 0.f, m = -1e30f;
    for (int c = 0; c < C_; ++c) {
        float v = x2[((size_t)b * C_ + c) * N_ + n] * cal[c];
        s += v; m = fmaxf(m, v);
    }
    sain[((size_t)b * 2 + 0) * N_ + n] = s * (1.f / C_);
    sain[((size_t)b * 2 + 1) * N_ + n] = m;
}

// ---------------- final: sa conv + sigmoid + output (f32) ----------------
__global__ __launch_bounds__(256) void k_final(const float* __restrict__ x2,
                                               const float* __restrict__ ca,
                                               const float* __restrict__ sain,
                                               const float* __restrict__ wsa,
                                               float* __restrict__ out) {
    int b = blockIdx.y;
    int n = blockIdx.x * 256 + threadIdx.x;
    __shared__ float cal[C_];
    cal[threadIdx.x] = ca[b * C_ + threadIdx.x];
    __syncthreads();
    int hh = n >> 6, ww = n & 63;
    float acc = 0.f;
#pragma unroll
    for (int i = 0; i < 2; ++i)
#pragma unroll
        for (int kh = 0; kh < 3; ++kh) {
            int hh2 = hh + kh - 1;
            if (hh2 < 0 || hh2 >= 64) continue;
#pragma unroll
            for (int kw = 0; kw < 3; ++kw) {
                int ww2 = ww + kw - 1;
                if (ww2 < 0 || ww2 >= 64) continue;
                acc += sain[((size_t)b * 2 + i) * N_ + hh2 * 64 + ww2] * wsa[i * 9 + kh * 3 + kw];
            }
        }
    float sa = 1.f / (1.f + __expf(-acc));
    for (int c = 0; c < C_; ++c) {
        size_t idx = ((size_t)b * C_ + c) * N_ + n;
        out[idx] = x2[idx] * cal[c] * sa;
    }
}

extern "C" void kernel_launch(void* const* d_in, const int* in_sizes, int n_in,
                              void* d_out, int out_size, void* d_ws, size_t ws_size,
                              hipStream_t stream) {
    const float* x     = (const float*)d_in[0];
    const float* wqkv  = (const float*)d_in[1];
    const float* bqkv  = (const float*)d_in[2];
    const float* wproj = (const float*)d_in[3];
    const float* bproj = (const float*)d_in[4];
    const float* wpe   = (const float*)d_in[5];
    const float* bpe   = (const float*)d_in[6];
    const float* wfc1  = (const float*)d_in[7];
    const float* wfc2  = (const float*)d_in[8];
    const float* wsa   = (const float*)d_in[9];
    float* out = (float*)d_out;

    char* ws = (char*)d_ws;
    size_t off = 0;
    auto alloc = [&](size_t bytes) {
        char* p = ws + off;
        off += (bytes + 255) & ~(size_t)255;
        return p;
    };
    bf16*  qt    = (bf16*)alloc((size_t)B_ * NH_ * N_ * KD_ * 2);
    bf16*  ktb   = (bf16*)alloc((size_t)B_ * NH_ * N_ * KD_ * 2);
    bf16*  vbuf  = (bf16*)alloc((size_t)B_ * NH_ * HD_ * N_ * 2);
    bf16*  xT    = (bf16*)alloc((size_t)B_ * N_ * C_ * 2);
    bf16*  attnT = (bf16*)alloc((size_t)B_ * N_ * C_ * 2);
    float* x2    = (float*)alloc((size_t)B_ * C_ * N_ * 4);
    bf16*  wqb   = (bf16*)alloc((size_t)HQKV_ * C_ * 2);
    bf16*  wpb   = (bf16*)alloc((size_t)C_ * C_ * 2);
    float* avg   = (float*)alloc(B_ * C_ * 4);
    float* mxb   = (float*)alloc(B_ * C_ * 4);
    float* cab   = (float*)alloc(B_ * C_ * 4);
    float* sain  = (float*)alloc((size_t)B_ * 2 * N_ * 4);
    bf16*  yT    = xT;  // alias: xT dead after k_qkv completes (stream-ordered)

    k_convw<<<dim3((HQKV_ * C_ + 255) / 256), 256, 0, stream>>>(wqkv, wproj, wqb, wpb);
    k_transpose<<<dim3(64, 4, B_), 256, 0, stream>>>(x, xT);
    k_qkv<<<dim3(64, 8, B_), 256, 0, stream>>>(wqb, xT, bqkv, qt, ktb, vbuf);
    k_attn<<<dim3(1024), 256, 0, stream>>>(qt, ktb, vbuf, attnT);
    k_pe_add<<<dim3(64, 4, B_), 256, 0, stream>>>(attnT, vbuf, wpe, bpe, yT);
    k_proj<<<dim3(64, 4, B_), 256, 0, stream>>>(wpb, yT, bproj, x, x2);
    k_ca_red<<<dim3(B_ * C_), 256, 0, stream>>>(x2, avg, mxb);
    k_ca_mlp<<<dim3(B_), 256, 0, stream>>>(avg, mxb, wfc1, wfc2, cab);
    k_sa_red<<<dim3(16, B_), 256, 0, stream>>>(x2, cab, sain);
    k_final<<<dim3(16, B_), 256, 0, stream>>>(x2, cab, sain, wsa, out);
}